// Round 2
// baseline (603.000 us; speedup 1.0000x reference)
//
#include <hip/hip_runtime.h>
#include <math.h>

// Problem constants (verified against setup_inputs): N=100000, L=6, D=128, H=8, C=4096
constexpr int L = 6, D = 128, H = 8;
constexpr int NT = 256;        // threads per block
constexpr int GROUPS = NT / 32; // 8 groups of 32 lanes; GROUPS == H
constexpr int CH = 16;         // feat rows staged per chunk in phase C

__global__ __launch_bounds__(NT) void readout_kernel(
    const float* __restrict__ feat,   // N*L*D
    const float* __restrict__ query,  // H*D
    const int*   __restrict__ cid,    // N (sorted, values in [0,C))
    float* __restrict__ comp_feat,    // C*H*D
    float* __restrict__ attn,         // N*L*H (used as temp logit storage, then final attn)
    float* __restrict__ comp_ids,     // C
    int N)
{
  const int c    = blockIdx.x;
  const int tid  = threadIdx.x;
  const int grp  = tid >> 5;
  const int lane = tid & 31;

  if (tid == 0) comp_ids[c] = (float)c;

  __shared__ int   s_range[2];
  __shared__ float s_m[GROUPS][H];
  __shared__ float s_s[GROUPS][H];
  __shared__ float s_M[H];
  __shared__ float s_S[H];
  __shared__ __align__(16) float s_rows[CH][D];   // 8 KB staging
  __shared__ float s_attn[CH][H];                 // 512 B

  if (tid == 0) {
    // lower_bound(c), lower_bound(c+1) over sorted cid
    int lo = 0, hi = N;
    while (lo < hi) { int mid = (lo + hi) >> 1; if (cid[mid] < c)     lo = mid + 1; else hi = mid; }
    s_range[0] = lo;
    hi = N; // lo already >= lower_bound(c)
    while (lo < hi) { int mid = (lo + hi) >> 1; if (cid[mid] < c + 1) lo = mid + 1; else hi = mid; }
    s_range[1] = lo;
  }

  // Cache query in registers: lane holds q4[h] = query[h][lane*4 .. lane*4+3]
  float4 q4[H];
  #pragma unroll
  for (int h = 0; h < H; ++h)
    q4[h] = *reinterpret_cast<const float4*>(&query[h * D + lane * 4]);

  __syncthreads();
  const int  s    = s_range[0];
  const int  e    = s_range[1];
  const int  rows = (e - s) * L;           // (node,layer) rows in this component
  const long base = (long)s * L;           // row offset in the N*L row space

  // ---------- Phase A: logits + online per-group (m, sum) ----------
  float m[H], sum[H];
  #pragma unroll
  for (int h = 0; h < H; ++h) { m[h] = -INFINITY; sum[h] = 0.f; }

  for (int r = grp; r < rows; r += GROUPS) {
    const float4 f4 = *reinterpret_cast<const float4*>(&feat[(base + r) * D + lane * 4]);
    float keep = 0.f;
    #pragma unroll
    for (int h = 0; h < H; ++h) {
      float v = f4.x * q4[h].x + f4.y * q4[h].y + f4.z * q4[h].z + f4.w * q4[h].w;
      v += __shfl_xor(v, 1);
      v += __shfl_xor(v, 2);
      v += __shfl_xor(v, 4);
      v += __shfl_xor(v, 8);
      v += __shfl_xor(v, 16);
      // v = logit(row r, head h) on all 32 lanes of this group
      if (lane == h) keep = v;
      const float nm = fmaxf(m[h], v);
      sum[h] = sum[h] * expf(m[h] - nm) + expf(v - nm);
      m[h] = nm;
    }
    if (lane < H) attn[(base + r) * H + lane] = keep;  // park logits
  }

  if (lane == 0) {
    #pragma unroll
    for (int h = 0; h < H; ++h) { s_m[grp][h] = m[h]; s_s[grp][h] = sum[h]; }
  }
  __syncthreads();

  if (tid < H) {
    const int h = tid;
    float M = -INFINITY;
    #pragma unroll
    for (int g = 0; g < GROUPS; ++g) M = fmaxf(M, s_m[g][h]);
    float S = 0.f;
    #pragma unroll
    for (int g = 0; g < GROUPS; ++g) {
      const float sg = s_s[g][h];
      if (sg > 0.f) S += sg * expf(s_m[g][h] - M);
    }
    s_M[h] = M;
    s_S[h] = S;
  }
  __syncthreads();

  // ---------- Phase C: final attn + weighted feature accumulation ----------
  // Thread owns (head hh, float4 at d = lane*4) of the C,H,D accumulator.
  const int hh = grp;   // GROUPS == H
  float4 acc = {0.f, 0.f, 0.f, 0.f};

  for (int b = 0; b < rows; b += CH) {
    const int nrow = min(CH, rows - b);

    // stage contiguous feat rows into LDS
    const float4* src = reinterpret_cast<const float4*>(&feat[(base + b) * D]);
    for (int i = tid; i < nrow * (D / 4); i += NT)
      reinterpret_cast<float4*>(s_rows)[i] = src[i];

    // finalize attn for the chunk (read parked logits, write final attn)
    for (int i = tid; i < nrow * H; i += NT) {
      const int  r   = i / H;
      const int  h   = i - r * H;
      const long idx = (base + b + r) * H + h;
      const float a  = expf(attn[idx] - s_M[h]) / s_S[h];
      attn[idx]   = a;
      s_attn[r][h] = a;
    }
    __syncthreads();

    for (int r = 0; r < nrow; ++r) {
      const float  w = s_attn[r][hh];
      const float4 f = *reinterpret_cast<const float4*>(&s_rows[r][lane * 4]);
      acc.x += w * f.x; acc.y += w * f.y; acc.z += w * f.z; acc.w += w * f.w;
    }
    __syncthreads();
  }

  *reinterpret_cast<float4*>(&comp_feat[((long)c * H + hh) * D + lane * 4]) = acc;
}

extern "C" void kernel_launch(void* const* d_in, const int* in_sizes, int n_in,
                              void* d_out, int out_size, void* d_ws, size_t ws_size,
                              hipStream_t stream) {
  const float* feat  = (const float*)d_in[0];
  const float* query = (const float*)d_in[1];
  const int*   cid   = (const int*)d_in[2];

  const int N = in_sizes[2];                      // 100000
  // out_size = C*H*D + N*L*H + C  =>  C = (out_size - N*L*H) / (H*D + 1)
  const int C = (out_size - N * L * H) / (H * D + 1);   // 4096

  float* comp_feat = (float*)d_out;
  float* attn      = comp_feat + (size_t)C * H * D;
  float* comp_ids  = attn + (size_t)N * L * H;

  readout_kernel<<<C, NT, 0, stream>>>(feat, query, cid, comp_feat, attn, comp_ids, N);
}